// Round 21
// baseline (38.137 us; speedup 1.0000x reference)
//
#include <hip/hip_runtime.h>
#include <hip/hip_bf16.h>

// B=8, T=2048, E=1024, H=64 single-head causal attention.
// ws: wsT bf16 [192][1024] @0 ; kF/qF @1MB/@3MB fragment-tiled K/Q;
// vF @5MB fragment-tiled V.
// = round-13 best config, with proj epilogue stores made NON-TEMPORAL so
//   kF/qF/vF land clean in L3 instead of dirty in the producer XCD's L2
//   (attn reads them from a different XCD; remote-dirty snoops were the
//   suspected ~20us first-touch cost).

typedef float f32x4 __attribute__((ext_vector_type(4)));
typedef float f32x16 __attribute__((ext_vector_type(16)));
typedef short bf16x8 __attribute__((ext_vector_type(8)));
typedef short bf16x4 __attribute__((ext_vector_type(4)));
typedef unsigned u32x2 __attribute__((ext_vector_type(2)));

#define MFMA16 __builtin_amdgcn_mfma_f32_16x16x32_bf16
#define MFMA32 __builtin_amdgcn_mfma_f32_32x32x16_bf16

__device__ __forceinline__ short f2bf(float f) {
    union { float f; unsigned u; } c; c.f = f;
    unsigned u = c.u;
    return (short)((u + 0x7FFFu + ((u >> 16) & 1u)) >> 16);  // RNE
}

__device__ __forceinline__ unsigned cvt_pk_bf16(float lo, float hi) {
    unsigned r;
    asm("v_cvt_pk_bf16_f32 %0, %1, %2" : "=v"(r) : "v"(lo), "v"(hi));
    return r;
}

__device__ __forceinline__ float exp2_fast(float x) {
    float r; asm("v_exp_f32 %0, %1" : "=v"(r) : "v"(x)); return r;
}
__device__ __forceinline__ float rcp_fast(float x) {
    float r; asm("v_rcp_f32 %0, %1" : "=v"(r) : "v"(x)); return r;
}

// ---- kernel 0: transpose+convert W -> wsT[192][1024] bf16; Wq scaled 0.125*log2e
__global__ __launch_bounds__(256) void prep_w(const float* __restrict__ Wk,
                                              const float* __restrict__ Wq,
                                              const float* __restrict__ Wv,
                                              short* __restrict__ wsT) {
    int idx = blockIdx.x * 256 + threadIdx.x;
    int r = idx >> 10;
    int k = idx & 1023;
    int mat = r >> 6, c = r & 63;
    const float* W = (mat == 0) ? Wk : (mat == 1) ? Wq : Wv;
    float v = W[k * 64 + c];
    if (mat == 1) v *= 0.125f * 1.44269504088896f;   // fold scale + log2(e)
    wsT[r * 1024 + k] = f2bf(v);
}

// ---- kernel 1: projections; ONLY change vs rounds 7-20: epilogue stores
// are non-temporal (global_store_* nt) so outputs land clean in L3.
__global__ __launch_bounds__(512, 4) void proj(const float* __restrict__ x,
                                               const short* __restrict__ wsT,
                                               short* __restrict__ kF,
                                               short* __restrict__ qF,
                                               short* __restrict__ vF) {
    __shared__ char ldsraw[2 * 8192 + 2 * 24576];   // xbuf[2] then wbuf[2]
    int tid = threadIdx.x;
    int w = tid >> 6, lane = tid & 63;
    int wm = w >> 2, wn = w & 3;
    int lr = lane & 15, lg = lane >> 4;
    int t0 = blockIdx.x * 32;

    f32x4 acc[3] = {};

    auto stage = [&](int kt, int buf) {
        int k0 = kt * 64;
        {
            int G = tid;
            int row = G >> 4, p = G & 15;
            int g = p ^ (row & 15);
            const float* gp = x + (size_t)(t0 + row) * 1024 + k0 + g * 4;
            unsigned base = (unsigned)(buf * 8192 + w * 1024);
            __builtin_amdgcn_global_load_lds(
                (const __attribute__((address_space(1))) void*)gp,
                (__attribute__((address_space(3))) void*)(ldsraw + base), 16, 0, 0);
        }
#pragma unroll
        for (int s = 0; s < 3; ++s) {
            int G = s * 512 + tid;
            int row = G >> 3, p = G & 7;
            int g = p ^ (row & 7);
            const short* gp = wsT + (size_t)row * 1024 + k0 + g * 8;
            unsigned base = (unsigned)(16384 + buf * 24576 + s * 8192 + w * 1024);
            __builtin_amdgcn_global_load_lds(
                (const __attribute__((address_space(1))) void*)gp,
                (__attribute__((address_space(3))) void*)(ldsraw + base), 16, 0, 0);
        }
    };

    int arow = wm * 16 + lr;

    stage(0, 0);
    __syncthreads();

    for (int kt = 0; kt < 16; ++kt) {
        int cur = kt & 1;
        if (kt < 15) stage(kt + 1, cur ^ 1);

        const char* xb = ldsraw + cur * 8192 + arow * 256;
        const char* wb = ldsraw + 16384 + cur * 24576;
#pragma unroll
        for (int ks = 0; ks < 2; ++ks) {
            int g0 = ks * 8 + lg * 2;
            f32x4 u0 = *(const f32x4*)(xb + ((g0)     ^ lr) * 16);
            f32x4 u1 = *(const f32x4*)(xb + ((g0 + 1) ^ lr) * 16);
            bf16x8 a;
#pragma unroll
            for (int j = 0; j < 4; ++j) { a[j] = f2bf(u0[j]); a[4 + j] = f2bf(u1[j]); }
            int slot = (ks * 4 + lg) ^ (lr & 7);
#pragma unroll
            for (int nt = 0; nt < 3; ++nt) {
                int brow = wn * 48 + nt * 16 + lr;
                bf16x8 bf = *(const bf16x8*)(wb + brow * 128 + slot * 16);
                acc[nt] = MFMA16(a, bf, acc[nt], 0, 0, 0);
            }
        }
        __syncthreads();
    }

    int tg = t0 + wm * 16 + lg * 4;
    int b = tg >> 11;
    int s = (tg & 2047) >> 5;
    int w32b = tg & 31;
#pragma unroll
    for (int nt = 0; nt < 3; ++nt) {
        int col0 = wn * 48 + nt * 16;
        int mat = col0 >> 6;
        int h = (col0 & 63) + lr;
        if (mat == 2) {
            int ht = h >> 5;
            int c = w32b >> 4;
            int hi2 = (lg >> 1) & 1;
            int jb = (lg & 1) * 4;
            int lanep = hi2 * 32 + (h & 31);
            bf16x4 pk;
#pragma unroll
            for (int r = 0; r < 4; ++r) pk[r] = f2bf(acc[nt][r]);
            size_t idx = (((((size_t)b * 64 + s) * 2 + ht) * 2 + c) * 64 + lanep) * 8 + jb;
            __builtin_nontemporal_store(pk, (bf16x4*)(vF + idx));
        } else {
            short* dst = mat ? qF : kF;
            int c = h >> 4, hi2 = (h >> 3) & 1, j = h & 7;
            size_t base = ((((size_t)b * 64 + s) * 4 + c) * 64 + hi2 * 32) * 8 + j;
#pragma unroll
            for (int r = 0; r < 4; ++r)
                __builtin_nontemporal_store(f2bf(acc[nt][r]),
                                            dst + base + (size_t)(w32b + r) * 8);
        }
    }
}

// ---- kernel 2: causal flash attention (round-13 best, BYTE-IDENTICAL).
__global__ __launch_bounds__(512, 4) void attn(const short* __restrict__ kF,
                                               const short* __restrict__ qF,
                                               const short* __restrict__ vF,
                                               float* __restrict__ out) {
    int bid = blockIdx.x;
    int b = bid & 7;                             // one batch per XCD
    int k = (bid >> 3) & 31;
    int half = bid >> 8;
    int ti = half ? (63 - k) : k;                // CU-complementary pairing
    int t0 = ti * 32;
    int nblk = ti + 1;

    int w = threadIdx.x >> 6;                    // kv-split 0..7
    int lane = threadIdx.x & 63;
    int q = lane & 31, hi = lane >> 5;
    int tid = threadIdx.x;

    __shared__ float lacc[8][32][65];            // 66.6 KB
    __shared__ float lm[8][32], ll[8][32];
    __shared__ float sjl[8][32], linv[32];

    const short* qp = qF + ((size_t)(b * 64 + ti)) * 2048 + lane * 8;
    bf16x8 qf0 = *(const bf16x8*)(qp);
    bf16x8 qf1 = *(const bf16x8*)(qp + 512);
    bf16x8 qf2 = *(const bf16x8*)(qp + 1024);
    bf16x8 qf3 = *(const bf16x8*)(qp + 1536);

    const short* kb_b = kF + (size_t)b * 64 * 2048 + lane * 8;
    const short* vb_b = vF + (size_t)b * 64 * 2048 + lane * 8;

    f32x16 acc0 = {}, acc1 = {};
    float m_s = -1e30f, l_s = 0.f;

    for (int blk = w; blk < nblk; blk += 8) {
        const short* kp = kb_b + (size_t)blk * 2048;
        bf16x8 kf0 = *(const bf16x8*)(kp);
        bf16x8 kf1 = *(const bf16x8*)(kp + 512);
        bf16x8 kf2 = *(const bf16x8*)(kp + 1024);
        bf16x8 kf3 = *(const bf16x8*)(kp + 1536);

        f32x16 S = {};
        S = MFMA32(kf0, qf0, S, 0, 0, 0);
        S = MFMA32(kf1, qf1, S, 0, 0, 0);
        S = MFMA32(kf2, qf2, S, 0, 0, 0);
        S = MFMA32(kf3, qf3, S, 0, 0, 0);

        const short* vp = vb_b + (size_t)blk * 2048;
        bf16x8 vc0 = *(const bf16x8*)(vp);
        bf16x8 vc1 = *(const bf16x8*)(vp + 512);
        bf16x8 vc2 = *(const bf16x8*)(vp + 1024);
        bf16x8 vc3 = *(const bf16x8*)(vp + 1536);

        if (blk == ti) {                         // diagonal: mask kv>q
#pragma unroll
            for (int r = 0; r < 16; ++r) {
                int row = (r & 3) + 8 * (r >> 2) + 4 * hi;
                if (row > q) S[r] = -1e30f;
            }
        }

        // max tree shaped for v_max3
        float t0m = fmaxf(fmaxf(S[0], S[1]), S[2]);
        float t1m = fmaxf(fmaxf(S[3], S[4]), S[5]);
        float t2m = fmaxf(fmaxf(S[6], S[7]), S[8]);
        float t3m = fmaxf(fmaxf(S[9], S[10]), S[11]);
        float t4m = fmaxf(fmaxf(S[12], S[13]), S[14]);
        float tm = fmaxf(fmaxf(fmaxf(t0m, t1m), fmaxf(t2m, t3m)),
                         fmaxf(t4m, S[15]));
        tm = fmaxf(tm, __shfl_xor(tm, 32));

        bool skip = __all(tm <= m_s + 11.5f);    // defer-rescale (P <= 2^11.5)
        float mn = skip ? m_s : fmaxf(m_s, tm);

#pragma unroll
        for (int r = 0; r < 16; ++r) S[r] = exp2_fast(S[r] - mn);
        float b0 = (S[0] + S[1]) + (S[2] + S[3]);
        float b1 = (S[4] + S[5]) + (S[6] + S[7]);
        float b2 = (S[8] + S[9]) + (S[10] + S[11]);
        float b3 = (S[12] + S[13]) + (S[14] + S[15]);
        float rs = (b0 + b1) + (b2 + b3);
        rs += __shfl_xor(rs, 32);

        if (skip) {
            l_s += rs;
        } else {
            float fr = exp2_fast(m_s - mn);
            l_s = l_s * fr + rs;
            m_s = mn;
#pragma unroll
            for (int r = 0; r < 16; ++r) { acc0[r] *= fr; acc1[r] *= fr; }
        }

        unsigned pk0 = cvt_pk_bf16(S[0],  S[1]);
        unsigned pk1 = cvt_pk_bf16(S[2],  S[3]);
        unsigned pk2 = cvt_pk_bf16(S[4],  S[5]);
        unsigned pk3 = cvt_pk_bf16(S[6],  S[7]);
        unsigned pk4 = cvt_pk_bf16(S[8],  S[9]);
        unsigned pk5 = cvt_pk_bf16(S[10], S[11]);
        unsigned pk6 = cvt_pk_bf16(S[12], S[13]);
        unsigned pk7 = cvt_pk_bf16(S[14], S[15]);
        u32x2 s02 = __builtin_amdgcn_permlane32_swap(pk0, pk2, false, false);
        u32x2 s13 = __builtin_amdgcn_permlane32_swap(pk1, pk3, false, false);
        u32x2 s46 = __builtin_amdgcn_permlane32_swap(pk4, pk6, false, false);
        u32x2 s57 = __builtin_amdgcn_permlane32_swap(pk5, pk7, false, false);
        union { bf16x8 v; unsigned u[4]; } f0, f1;
        f0.u[0] = s02.x; f0.u[1] = s13.x; f0.u[2] = s02.y; f0.u[3] = s13.y;
        f1.u[0] = s46.x; f1.u[1] = s57.x; f1.u[2] = s46.y; f1.u[3] = s57.y;

        acc0 = MFMA32(vc0, f0.v, acc0, 0, 0, 0);
        acc0 = MFMA32(vc1, f1.v, acc0, 0, 0, 0);
        acc1 = MFMA32(vc2, f0.v, acc1, 0, 0, 0);
        acc1 = MFMA32(vc3, f1.v, acc1, 0, 0, 0);
    }

    // publish partials
    if (hi == 0) { lm[w][q] = m_s; ll[w][q] = l_s; }
#pragma unroll
    for (int r = 0; r < 16; ++r) {
        int row = (r & 3) + 8 * (r >> 2) + 4 * hi;
        lacc[w][q][row]      = acc0[r];
        lacc[w][q][32 + row] = acc1[r];
    }
    __syncthreads();

    // merge phase A: 32 threads compute per-row scales + 1/lsum once
    if (tid < 32) {
        int row = tid;
        float ms = lm[0][row];
#pragma unroll
        for (int jj = 1; jj < 8; ++jj) ms = fmaxf(ms, lm[jj][row]);
        float lsum = 0.f;
#pragma unroll
        for (int jj = 0; jj < 8; ++jj) {
            float sj = exp2_fast(lm[jj][row] - ms);
            sjl[jj][row] = sj;
            lsum += ll[jj][row] * sj;
        }
        linv[row] = rcp_fast(lsum);
    }
    __syncthreads();

    // merge phase B: 512 threads x 4 elems = 32x64 outputs, 8 FMA each
#pragma unroll
    for (int e = 0; e < 4; ++e) {
        int elem = e * 512 + tid;
        int row = elem >> 6, col = elem & 63;
        float asum = 0.f;
#pragma unroll
        for (int jj = 0; jj < 8; ++jj)
            asum += lacc[jj][row][col] * sjl[jj][row];
        out[(size_t)(b * 2048 + t0 + row) * 64 + col] = asum * linv[row];
    }
}

extern "C" void kernel_launch(void* const* d_in, const int* in_sizes, int n_in,
                              void* d_out, int out_size, void* d_ws, size_t ws_size,
                              hipStream_t stream) {
    (void)in_sizes; (void)n_in; (void)out_size; (void)ws_size;
    const float* x  = (const float*)d_in[0];
    const float* Wk = (const float*)d_in[1];
    const float* Wq = (const float*)d_in[2];
    const float* Wv = (const float*)d_in[3];
    float* out = (float*)d_out;

    char* ws = (char*)d_ws;
    short* wsT = (short*)(ws);                  // 384 KB
    short* kF  = (short*)(ws + (1u << 20));     // 2 MB
    short* qF  = (short*)(ws + (3u << 20));     // 2 MB
    short* vF  = (short*)(ws + (5u << 20));     // 2 MB

    prep_w<<<768, 256, 0, stream>>>(Wk, Wq, Wv, wsT);
    proj  <<<512, 512, 0, stream>>>(x, wsT, kF, qF, vF);
    attn  <<<512, 512, 0, stream>>>(kF, qF, vF, out);
}

// Round 22
// 35.786 us; speedup vs baseline: 1.0657x; 1.0657x over previous
//
#include <hip/hip_runtime.h>
#include <hip/hip_bf16.h>

// B=8, T=2048, E=1024, H=64 single-head causal attention.
// ws: wsT bf16 [192][1024] @0 ; kF/qF @1MB/@3MB fragment-tiled K/Q;
// vF @5MB fragment-tiled V.
// FINAL CONFIG (round 13/19 best, 35.8us): prep + LDS-staged proj +
// fragment-tiled flash attn (512 blocks, CU-complementary tile pairing,
// running-max online softmax + defer-rescale, raw v_exp/v_rcp, lean merge).

typedef float f32x4 __attribute__((ext_vector_type(4)));
typedef float f32x16 __attribute__((ext_vector_type(16)));
typedef short bf16x8 __attribute__((ext_vector_type(8)));
typedef short bf16x4 __attribute__((ext_vector_type(4)));
typedef unsigned u32x2 __attribute__((ext_vector_type(2)));

#define MFMA16 __builtin_amdgcn_mfma_f32_16x16x32_bf16
#define MFMA32 __builtin_amdgcn_mfma_f32_32x32x16_bf16

__device__ __forceinline__ short f2bf(float f) {
    union { float f; unsigned u; } c; c.f = f;
    unsigned u = c.u;
    return (short)((u + 0x7FFFu + ((u >> 16) & 1u)) >> 16);  // RNE
}

__device__ __forceinline__ unsigned cvt_pk_bf16(float lo, float hi) {
    unsigned r;
    asm("v_cvt_pk_bf16_f32 %0, %1, %2" : "=v"(r) : "v"(lo), "v"(hi));
    return r;
}

__device__ __forceinline__ float exp2_fast(float x) {
    float r; asm("v_exp_f32 %0, %1" : "=v"(r) : "v"(x)); return r;
}
__device__ __forceinline__ float rcp_fast(float x) {
    float r; asm("v_rcp_f32 %0, %1" : "=v"(r) : "v"(x)); return r;
}

// ---- kernel 0: transpose+convert W -> wsT[192][1024] bf16; Wq scaled 0.125*log2e
__global__ __launch_bounds__(256) void prep_w(const float* __restrict__ Wk,
                                              const float* __restrict__ Wq,
                                              const float* __restrict__ Wv,
                                              short* __restrict__ wsT) {
    int idx = blockIdx.x * 256 + threadIdx.x;
    int r = idx >> 10;
    int k = idx & 1023;
    int mat = r >> 6, c = r & 63;
    const float* W = (mat == 0) ? Wk : (mat == 1) ? Wq : Wv;
    float v = W[k * 64 + c];
    if (mat == 1) v *= 0.125f * 1.44269504088896f;   // fold scale + log2(e)
    wsT[r * 1024 + k] = f2bf(v);
}

// ---- kernel 1: projections (round-13 form; plain stores).
__global__ __launch_bounds__(512, 4) void proj(const float* __restrict__ x,
                                               const short* __restrict__ wsT,
                                               short* __restrict__ kF,
                                               short* __restrict__ qF,
                                               short* __restrict__ vF) {
    __shared__ char ldsraw[2 * 8192 + 2 * 24576];   // xbuf[2] then wbuf[2]
    int tid = threadIdx.x;
    int w = tid >> 6, lane = tid & 63;
    int wm = w >> 2, wn = w & 3;
    int lr = lane & 15, lg = lane >> 4;
    int t0 = blockIdx.x * 32;

    f32x4 acc[3] = {};

    auto stage = [&](int kt, int buf) {
        int k0 = kt * 64;
        {
            int G = tid;
            int row = G >> 4, p = G & 15;
            int g = p ^ (row & 15);
            const float* gp = x + (size_t)(t0 + row) * 1024 + k0 + g * 4;
            unsigned base = (unsigned)(buf * 8192 + w * 1024);
            __builtin_amdgcn_global_load_lds(
                (const __attribute__((address_space(1))) void*)gp,
                (__attribute__((address_space(3))) void*)(ldsraw + base), 16, 0, 0);
        }
#pragma unroll
        for (int s = 0; s < 3; ++s) {
            int G = s * 512 + tid;
            int row = G >> 3, p = G & 7;
            int g = p ^ (row & 7);
            const short* gp = wsT + (size_t)row * 1024 + k0 + g * 8;
            unsigned base = (unsigned)(16384 + buf * 24576 + s * 8192 + w * 1024);
            __builtin_amdgcn_global_load_lds(
                (const __attribute__((address_space(1))) void*)gp,
                (__attribute__((address_space(3))) void*)(ldsraw + base), 16, 0, 0);
        }
    };

    int arow = wm * 16 + lr;

    stage(0, 0);
    __syncthreads();

    for (int kt = 0; kt < 16; ++kt) {
        int cur = kt & 1;
        if (kt < 15) stage(kt + 1, cur ^ 1);

        const char* xb = ldsraw + cur * 8192 + arow * 256;
        const char* wb = ldsraw + 16384 + cur * 24576;
#pragma unroll
        for (int ks = 0; ks < 2; ++ks) {
            int g0 = ks * 8 + lg * 2;
            f32x4 u0 = *(const f32x4*)(xb + ((g0)     ^ lr) * 16);
            f32x4 u1 = *(const f32x4*)(xb + ((g0 + 1) ^ lr) * 16);
            bf16x8 a;
#pragma unroll
            for (int j = 0; j < 4; ++j) { a[j] = f2bf(u0[j]); a[4 + j] = f2bf(u1[j]); }
            int slot = (ks * 4 + lg) ^ (lr & 7);
#pragma unroll
            for (int nt = 0; nt < 3; ++nt) {
                int brow = wn * 48 + nt * 16 + lr;
                bf16x8 bf = *(const bf16x8*)(wb + brow * 128 + slot * 16);
                acc[nt] = MFMA16(a, bf, acc[nt], 0, 0, 0);
            }
        }
        __syncthreads();
    }

    int tg = t0 + wm * 16 + lg * 4;
    int b = tg >> 11;
    int s = (tg & 2047) >> 5;
    int w32b = tg & 31;
#pragma unroll
    for (int nt = 0; nt < 3; ++nt) {
        int col0 = wn * 48 + nt * 16;
        int mat = col0 >> 6;
        int h = (col0 & 63) + lr;
        if (mat == 2) {
            int ht = h >> 5;
            int c = w32b >> 4;
            int hi2 = (lg >> 1) & 1;
            int jb = (lg & 1) * 4;
            int lanep = hi2 * 32 + (h & 31);
            bf16x4 pk;
#pragma unroll
            for (int r = 0; r < 4; ++r) pk[r] = f2bf(acc[nt][r]);
            size_t idx = (((((size_t)b * 64 + s) * 2 + ht) * 2 + c) * 64 + lanep) * 8 + jb;
            *(bf16x4*)(vF + idx) = pk;
        } else {
            short* dst = mat ? qF : kF;
            int c = h >> 4, hi2 = (h >> 3) & 1, j = h & 7;
            size_t base = ((((size_t)b * 64 + s) * 4 + c) * 64 + hi2 * 32) * 8 + j;
#pragma unroll
            for (int r = 0; r < 4; ++r)
                dst[base + (size_t)(w32b + r) * 8] = f2bf(acc[nt][r]);
        }
    }
}

// ---- kernel 2: causal flash attention (round-13 best, BYTE-IDENTICAL).
__global__ __launch_bounds__(512, 4) void attn(const short* __restrict__ kF,
                                               const short* __restrict__ qF,
                                               const short* __restrict__ vF,
                                               float* __restrict__ out) {
    int bid = blockIdx.x;
    int b = bid & 7;                             // one batch per XCD
    int k = (bid >> 3) & 31;
    int half = bid >> 8;
    int ti = half ? (63 - k) : k;                // CU-complementary pairing
    int t0 = ti * 32;
    int nblk = ti + 1;

    int w = threadIdx.x >> 6;                    // kv-split 0..7
    int lane = threadIdx.x & 63;
    int q = lane & 31, hi = lane >> 5;
    int tid = threadIdx.x;

    __shared__ float lacc[8][32][65];            // 66.6 KB
    __shared__ float lm[8][32], ll[8][32];
    __shared__ float sjl[8][32], linv[32];

    const short* qp = qF + ((size_t)(b * 64 + ti)) * 2048 + lane * 8;
    bf16x8 qf0 = *(const bf16x8*)(qp);
    bf16x8 qf1 = *(const bf16x8*)(qp + 512);
    bf16x8 qf2 = *(const bf16x8*)(qp + 1024);
    bf16x8 qf3 = *(const bf16x8*)(qp + 1536);

    const short* kb_b = kF + (size_t)b * 64 * 2048 + lane * 8;
    const short* vb_b = vF + (size_t)b * 64 * 2048 + lane * 8;

    f32x16 acc0 = {}, acc1 = {};
    float m_s = -1e30f, l_s = 0.f;

    for (int blk = w; blk < nblk; blk += 8) {
        const short* kp = kb_b + (size_t)blk * 2048;
        bf16x8 kf0 = *(const bf16x8*)(kp);
        bf16x8 kf1 = *(const bf16x8*)(kp + 512);
        bf16x8 kf2 = *(const bf16x8*)(kp + 1024);
        bf16x8 kf3 = *(const bf16x8*)(kp + 1536);

        f32x16 S = {};
        S = MFMA32(kf0, qf0, S, 0, 0, 0);
        S = MFMA32(kf1, qf1, S, 0, 0, 0);
        S = MFMA32(kf2, qf2, S, 0, 0, 0);
        S = MFMA32(kf3, qf3, S, 0, 0, 0);

        const short* vp = vb_b + (size_t)blk * 2048;
        bf16x8 vc0 = *(const bf16x8*)(vp);
        bf16x8 vc1 = *(const bf16x8*)(vp + 512);
        bf16x8 vc2 = *(const bf16x8*)(vp + 1024);
        bf16x8 vc3 = *(const bf16x8*)(vp + 1536);

        if (blk == ti) {                         // diagonal: mask kv>q
#pragma unroll
            for (int r = 0; r < 16; ++r) {
                int row = (r & 3) + 8 * (r >> 2) + 4 * hi;
                if (row > q) S[r] = -1e30f;
            }
        }

        // max tree shaped for v_max3
        float t0m = fmaxf(fmaxf(S[0], S[1]), S[2]);
        float t1m = fmaxf(fmaxf(S[3], S[4]), S[5]);
        float t2m = fmaxf(fmaxf(S[6], S[7]), S[8]);
        float t3m = fmaxf(fmaxf(S[9], S[10]), S[11]);
        float t4m = fmaxf(fmaxf(S[12], S[13]), S[14]);
        float tm = fmaxf(fmaxf(fmaxf(t0m, t1m), fmaxf(t2m, t3m)),
                         fmaxf(t4m, S[15]));
        tm = fmaxf(tm, __shfl_xor(tm, 32));

        bool skip = __all(tm <= m_s + 11.5f);    // defer-rescale (P <= 2^11.5)
        float mn = skip ? m_s : fmaxf(m_s, tm);

#pragma unroll
        for (int r = 0; r < 16; ++r) S[r] = exp2_fast(S[r] - mn);
        float b0 = (S[0] + S[1]) + (S[2] + S[3]);
        float b1 = (S[4] + S[5]) + (S[6] + S[7]);
        float b2 = (S[8] + S[9]) + (S[10] + S[11]);
        float b3 = (S[12] + S[13]) + (S[14] + S[15]);
        float rs = (b0 + b1) + (b2 + b3);
        rs += __shfl_xor(rs, 32);

        if (skip) {
            l_s += rs;
        } else {
            float fr = exp2_fast(m_s - mn);
            l_s = l_s * fr + rs;
            m_s = mn;
#pragma unroll
            for (int r = 0; r < 16; ++r) { acc0[r] *= fr; acc1[r] *= fr; }
        }

        unsigned pk0 = cvt_pk_bf16(S[0],  S[1]);
        unsigned pk1 = cvt_pk_bf16(S[2],  S[3]);
        unsigned pk2 = cvt_pk_bf16(S[4],  S[5]);
        unsigned pk3 = cvt_pk_bf16(S[6],  S[7]);
        unsigned pk4 = cvt_pk_bf16(S[8],  S[9]);
        unsigned pk5 = cvt_pk_bf16(S[10], S[11]);
        unsigned pk6 = cvt_pk_bf16(S[12], S[13]);
        unsigned pk7 = cvt_pk_bf16(S[14], S[15]);
        u32x2 s02 = __builtin_amdgcn_permlane32_swap(pk0, pk2, false, false);
        u32x2 s13 = __builtin_amdgcn_permlane32_swap(pk1, pk3, false, false);
        u32x2 s46 = __builtin_amdgcn_permlane32_swap(pk4, pk6, false, false);
        u32x2 s57 = __builtin_amdgcn_permlane32_swap(pk5, pk7, false, false);
        union { bf16x8 v; unsigned u[4]; } f0, f1;
        f0.u[0] = s02.x; f0.u[1] = s13.x; f0.u[2] = s02.y; f0.u[3] = s13.y;
        f1.u[0] = s46.x; f1.u[1] = s57.x; f1.u[2] = s46.y; f1.u[3] = s57.y;

        acc0 = MFMA32(vc0, f0.v, acc0, 0, 0, 0);
        acc0 = MFMA32(vc1, f1.v, acc0, 0, 0, 0);
        acc1 = MFMA32(vc2, f0.v, acc1, 0, 0, 0);
        acc1 = MFMA32(vc3, f1.v, acc1, 0, 0, 0);
    }

    // publish partials
    if (hi == 0) { lm[w][q] = m_s; ll[w][q] = l_s; }
#pragma unroll
    for (int r = 0; r < 16; ++r) {
        int row = (r & 3) + 8 * (r >> 2) + 4 * hi;
        lacc[w][q][row]      = acc0[r];
        lacc[w][q][32 + row] = acc1[r];
    }
    __syncthreads();

    // merge phase A: 32 threads compute per-row scales + 1/lsum once
    if (tid < 32) {
        int row = tid;
        float ms = lm[0][row];
#pragma unroll
        for (int jj = 1; jj < 8; ++jj) ms = fmaxf(ms, lm[jj][row]);
        float lsum = 0.f;
#pragma unroll
        for (int jj = 0; jj < 8; ++jj) {
            float sj = exp2_fast(lm[jj][row] - ms);
            sjl[jj][row] = sj;
            lsum += ll[jj][row] * sj;
        }
        linv[row] = rcp_fast(lsum);
    }
    __syncthreads();

    // merge phase B: 512 threads x 4 elems = 32x64 outputs, 8 FMA each
#pragma unroll
    for (int e = 0; e < 4; ++e) {
        int elem = e * 512 + tid;
        int row = elem >> 6, col = elem & 63;
        float asum = 0.f;
#pragma unroll
        for (int jj = 0; jj < 8; ++jj)
            asum += lacc[jj][row][col] * sjl[jj][row];
        out[(size_t)(b * 2048 + t0 + row) * 64 + col] = asum * linv[row];
    }
}

extern "C" void kernel_launch(void* const* d_in, const int* in_sizes, int n_in,
                              void* d_out, int out_size, void* d_ws, size_t ws_size,
                              hipStream_t stream) {
    (void)in_sizes; (void)n_in; (void)out_size; (void)ws_size;
    const float* x  = (const float*)d_in[0];
    const float* Wk = (const float*)d_in[1];
    const float* Wq = (const float*)d_in[2];
    const float* Wv = (const float*)d_in[3];
    float* out = (float*)d_out;

    char* ws = (char*)d_ws;
    short* wsT = (short*)(ws);                  // 384 KB
    short* kF  = (short*)(ws + (1u << 20));     // 2 MB
    short* qF  = (short*)(ws + (3u << 20));     // 2 MB
    short* vF  = (short*)(ws + (5u << 20));     // 2 MB

    prep_w<<<768, 256, 0, stream>>>(Wk, Wq, Wv, wsT);
    proj  <<<512, 512, 0, stream>>>(x, wsT, kF, qF, vF);
    attn  <<<512, 512, 0, stream>>>(kF, qF, vF, out);
}